// Round 7
// baseline (26.666 us; speedup 1.0000x reference)
//
#include <hip/hip_runtime.h>

// HammingLoss: loss = mean_i popcount(code[output[i]] ^ code[target[i]])
// code[c] = 64-bit packing of coding_table[c, :] (values are exactly 0.0/1.0).
//
// ZERO-RMW-ATOMIC, 2-dispatch design.
//   R4->R5 established: ~1K device-scope RMW atomics at one address cost ~10 us
//   (serialized at the cross-XCD coherence point). So no counters, no fetch-add.
//
//   1) pack_init: table -> packed u64 codes (one 64-lane wave per class,
//      __ballot). Also plain-stores ~0ULL sentinels into all partial slots
//      (kernel-boundary completion is a release -> visible to dispatch 2).
//   2) hamming_finalize: int4 index loads (KBATCH batched up-front), LDS code
//      table, popcount-XOR, wave+block reduce; each block PUBLISHES its
//      partial with a device-scope RELEASE STORE (write-through, not RMW;
//      real partials <= 2^27 so they never equal the sentinel). Block
//      gridDim-1 then polls all slots with device-scope acquire loads until
//      no sentinel remains (all 1024 blocks are co-resident: 8KB LDS/256thr
//      -> ~8 blocks/CU capacity, so producers can't be starved), sums, and
//      writes out[0] = sum / n. Bounded sweep count -> fails loudly rather
//      than hanging if visibility assumptions are ever wrong.
//
// Working set (16.8 MB indices + table) is L2/L3-resident; do NOT use
// nontemporal loads.
//
// ws layout:
//   [0,    8000)   : unsigned long long codes[1000]
//   [8192, 16384)  : unsigned long long partials[MAIN_BLOCKS]

#define N_CLASSES 1000
#define CODE_LEN  64
#define MAIN_BLOCKS 1024
#define KBATCH 2
#define SENTINEL (~0ULL)

__global__ void pack_init_kernel(const float* __restrict__ table,
                                 unsigned long long* __restrict__ codes,
                                 unsigned long long* __restrict__ partials) {
    int gtid = blockIdx.x * blockDim.x + threadIdx.x;

    // sentinel-init the partials (plain stores; kernel boundary = release)
    if (gtid < MAIN_BLOCKS) partials[gtid] = SENTINEL;

    int wave = gtid >> 6;          // one 64-lane wave per class
    int lane = threadIdx.x & 63;
    if (wave < N_CLASSES) {
        float v = table[wave * CODE_LEN + lane];          // coalesced 256B/wave
        unsigned long long mask = __ballot(v > 0.5f);     // 64-bit ballot
        if (lane == 0) codes[wave] = mask;
    }
}

__global__ void __launch_bounds__(256)
hamming_finalize_kernel(const int* __restrict__ out_idx,
                        const int* __restrict__ tgt_idx,
                        const unsigned long long* __restrict__ codes,
                        unsigned long long* __restrict__ partials,
                        float* __restrict__ out,
                        int nvec, int n) {
    __shared__ unsigned long long s_codes[N_CLASSES];

    const int4* o4 = (const int4*)out_idx;
    const int4* t4 = (const int4*)tgt_idx;

    int tid0   = blockIdx.x * blockDim.x + threadIdx.x;
    int stride = gridDim.x * blockDim.x;

    // Issue all KBATCH iterations' global loads up-front: one latency
    // exposure, hidden under LDS staging + barrier. Static indexing only.
    int4 ob[KBATCH], tb[KBATCH];
    bool vb[KBATCH];
    #pragma unroll
    for (int k = 0; k < KBATCH; ++k) {
        int i = tid0 + k * stride;
        vb[k] = (i < nvec);
        if (vb[k]) { ob[k] = o4[i]; tb[k] = t4[i]; }
    }

    // stage packed table (8 KB) as 16B vectors
    {
        const ulonglong2* src = (const ulonglong2*)codes;
        ulonglong2*       dst = (ulonglong2*)s_codes;
        for (int i = threadIdx.x; i < N_CLASSES / 2; i += blockDim.x)
            dst[i] = src[i];
    }
    __syncthreads();

    int sum = 0;
    #pragma unroll
    for (int k = 0; k < KBATCH; ++k) {
        if (vb[k]) {
            sum += __popcll(s_codes[ob[k].x] ^ s_codes[tb[k].x]);
            sum += __popcll(s_codes[ob[k].y] ^ s_codes[tb[k].y]);
            sum += __popcll(s_codes[ob[k].z] ^ s_codes[tb[k].z]);
            sum += __popcll(s_codes[ob[k].w] ^ s_codes[tb[k].w]);
        }
    }
    // iterations beyond KBATCH (not taken at B=2M with 1024 blocks)
    for (int i = tid0 + KBATCH * stride; i < nvec; i += stride) {
        int4 o = o4[i];
        int4 t = t4[i];
        sum += __popcll(s_codes[o.x] ^ s_codes[t.x]);
        sum += __popcll(s_codes[o.y] ^ s_codes[t.y]);
        sum += __popcll(s_codes[o.z] ^ s_codes[t.z]);
        sum += __popcll(s_codes[o.w] ^ s_codes[t.w]);
    }
    // scalar tail (n % 4)
    for (int i = nvec * 4 + tid0; i < n; i += stride) {
        sum += __popcll(s_codes[out_idx[i]] ^ s_codes[tgt_idx[i]]);
    }

    // 64-lane wave reduce
    #pragma unroll
    for (int off = 32; off >= 1; off >>= 1)
        sum += __shfl_down(sum, off);

    __shared__ int s_part[4];      // 256 threads = 4 waves
    int wid  = threadIdx.x >> 6;
    int lane = threadIdx.x & 63;
    if (lane == 0) s_part[wid] = sum;
    __syncthreads();

    if (threadIdx.x == 0) {
        unsigned long long tot =
            (unsigned long long)(s_part[0] + s_part[1] + s_part[2] + s_part[3]);
        // device-scope release store (write-through; NOT a serialized RMW)
        __hip_atomic_store(&partials[blockIdx.x], tot,
                           __ATOMIC_RELEASE, __HIP_MEMORY_SCOPE_AGENT);
    }

    // designated finalizer: last block's wave 0 polls + reduces
    if (blockIdx.x == gridDim.x - 1 && threadIdx.x < 64) {
        int nblocks = gridDim.x;
        int sweeps  = (nblocks + 63) / 64;                // <=16
        unsigned long long lsum = 0;
        for (long attempt = 0; attempt < (1L << 22); ++attempt) {
            lsum = 0;
            bool incomplete = false;
            for (int k = 0; k < sweeps; ++k) {
                int i = threadIdx.x + k * 64;
                unsigned long long x = 0;
                if (i < nblocks)
                    x = __hip_atomic_load(&partials[i],
                                          __ATOMIC_ACQUIRE,
                                          __HIP_MEMORY_SCOPE_AGENT);
                if (x == SENTINEL) incomplete = true;
                else               lsum += x;
            }
            if (__ballot(incomplete) == 0ULL) break;      // all published
            __builtin_amdgcn_s_sleep(1);
        }
        // 64-lane reduce of lsum
        #pragma unroll
        for (int off = 32; off >= 1; off >>= 1)
            lsum += __shfl_down(lsum, off);
        if (threadIdx.x == 0)
            out[0] = (float)((double)lsum / (double)n);
    }
}

extern "C" void kernel_launch(void* const* d_in, const int* in_sizes, int n_in,
                              void* d_out, int out_size, void* d_ws, size_t ws_size,
                              hipStream_t stream) {
    const int*   out_idx = (const int*)d_in[0];
    const int*   tgt_idx = (const int*)d_in[1];
    const float* table   = (const float*)d_in[2];
    float*       out     = (float*)d_out;

    int n = in_sizes[0];

    unsigned long long* codes    = (unsigned long long*)d_ws;
    unsigned long long* partials = (unsigned long long*)((char*)d_ws + 8192);

    // 1) pack table -> u64 codes; sentinel-init partials
    {
        int threads = 256;                               // 4 waves/block
        int blocks = (N_CLASSES * 64 + threads - 1) / threads;  // 250
        pack_init_kernel<<<blocks, threads, 0, stream>>>(table, codes, partials);
    }

    // 2) main reduce + sentinel-poll finalize (single node)
    {
        int nvec = n / 4;
        int threads = 256;
        int nblocks = MAIN_BLOCKS;                       // 2 int4 iters/thread at B=2M
        int max_blocks = (nvec + threads - 1) / threads;
        if (nblocks > max_blocks) nblocks = max_blocks;
        if (nblocks < 1) nblocks = 1;
        hamming_finalize_kernel<<<nblocks, threads, 0, stream>>>(
            out_idx, tgt_idx, codes, partials, out, nvec, n);
    }
}

// Round 8
// 15.847 us; speedup vs baseline: 1.6828x; 1.6828x over previous
//
#include <hip/hip_runtime.h>

// HammingLoss: loss = mean_i popcount(code[output[i]] ^ code[target[i]])
// code[c] = 64-bit packing of coding_table[c, :] (values are exactly 0.0/1.0).
//
// ZERO-SYNC design — the kernel boundary is the ONLY cross-block release.
// Hard-won constraints (keep!):
//   R4->R5: ~1K device-scope RMW atomics at one address = ~10 us (serialized
//           at the cross-XCD coherence point). No counters, no fetch-add.
//   R6->R7: device-scope release/acquire polling (sentinel fusion) = +11 us
//           (AGENT-scope stores/loads -> L2 writeback/invalidate traffic).
//           Node fusion via in-kernel sync is NEVER worth the ~1-2 us a
//           dispatch node costs. Plain stores + separate dispatch wins.
//
// 3 dispatches:
//   1) pack_init: table -> packed u64 codes (one 64-lane wave per class,
//      __ballot). Nothing to zero: partials/out are fully rewritten each call.
//   2) hamming: 2048 blocks x 1 int4-pair per thread (max TLP; loads issued
//      before LDS staging so HBM/L2 latency hides under staging + barrier),
//      LDS code table, popcount-XOR, wave+block reduce, plain store of block
//      partial.
//   3) finalize: 512 threads, coalesced partial loads (2048 * 8B = 16 KB),
//      wave shfl + LDS tree, out = sum / n.
//
// Working set (16.8 MB indices + table) is L2/L3-resident; do NOT use
// nontemporal loads.
//
// ws layout:
//   [0,    8000)   : unsigned long long codes[1000]
//   [8192, 24576)  : unsigned long long partials[MAIN_BLOCKS]

#define N_CLASSES 1000
#define CODE_LEN  64
#define MAIN_BLOCKS 2048
#define KBATCH 1

__global__ void pack_init_kernel(const float* __restrict__ table,
                                 unsigned long long* __restrict__ codes) {
    int gtid = blockIdx.x * blockDim.x + threadIdx.x;
    int wave = gtid >> 6;          // one 64-lane wave per class
    int lane = threadIdx.x & 63;
    if (wave < N_CLASSES) {
        float v = table[wave * CODE_LEN + lane];          // coalesced 256B/wave
        unsigned long long mask = __ballot(v > 0.5f);     // 64-bit ballot
        if (lane == 0) codes[wave] = mask;
    }
}

__global__ void __launch_bounds__(256)
hamming_kernel(const int* __restrict__ out_idx,
               const int* __restrict__ tgt_idx,
               const unsigned long long* __restrict__ codes,
               unsigned long long* __restrict__ partials,
               int nvec, int n) {
    __shared__ unsigned long long s_codes[N_CLASSES];

    const int4* o4 = (const int4*)out_idx;
    const int4* t4 = (const int4*)tgt_idx;

    int tid0   = blockIdx.x * blockDim.x + threadIdx.x;
    int stride = gridDim.x * blockDim.x;

    // Issue the KBATCH iterations' global loads up-front: one latency
    // exposure, hidden under LDS staging + barrier. Static indexing only.
    int4 ob[KBATCH], tb[KBATCH];
    bool vb[KBATCH];
    #pragma unroll
    for (int k = 0; k < KBATCH; ++k) {
        int i = tid0 + k * stride;
        vb[k] = (i < nvec);
        if (vb[k]) { ob[k] = o4[i]; tb[k] = t4[i]; }
    }

    // stage packed table (8 KB) as 16B vectors
    {
        const ulonglong2* src = (const ulonglong2*)codes;
        ulonglong2*       dst = (ulonglong2*)s_codes;
        for (int i = threadIdx.x; i < N_CLASSES / 2; i += blockDim.x)
            dst[i] = src[i];
    }
    __syncthreads();

    int sum = 0;
    #pragma unroll
    for (int k = 0; k < KBATCH; ++k) {
        if (vb[k]) {
            sum += __popcll(s_codes[ob[k].x] ^ s_codes[tb[k].x]);
            sum += __popcll(s_codes[ob[k].y] ^ s_codes[tb[k].y]);
            sum += __popcll(s_codes[ob[k].z] ^ s_codes[tb[k].z]);
            sum += __popcll(s_codes[ob[k].w] ^ s_codes[tb[k].w]);
        }
    }
    // iterations beyond KBATCH (not taken at B=2M with 2048 blocks)
    for (int i = tid0 + KBATCH * stride; i < nvec; i += stride) {
        int4 o = o4[i];
        int4 t = t4[i];
        sum += __popcll(s_codes[o.x] ^ s_codes[t.x]);
        sum += __popcll(s_codes[o.y] ^ s_codes[t.y]);
        sum += __popcll(s_codes[o.z] ^ s_codes[t.z]);
        sum += __popcll(s_codes[o.w] ^ s_codes[t.w]);
    }
    // scalar tail (n % 4)
    for (int i = nvec * 4 + tid0; i < n; i += stride) {
        sum += __popcll(s_codes[out_idx[i]] ^ s_codes[tgt_idx[i]]);
    }

    // 64-lane wave reduce
    #pragma unroll
    for (int off = 32; off >= 1; off >>= 1)
        sum += __shfl_down(sum, off);

    __shared__ int s_part[4];      // 256 threads = 4 waves
    int wid  = threadIdx.x >> 6;
    int lane = threadIdx.x & 63;
    if (lane == 0) s_part[wid] = sum;
    __syncthreads();

    if (threadIdx.x == 0) {
        partials[blockIdx.x] =
            (unsigned long long)(s_part[0] + s_part[1] + s_part[2] + s_part[3]);
    }
}

__global__ void __launch_bounds__(512)
finalize_kernel(const unsigned long long* __restrict__ partials,
                float* __restrict__ out, int nblocks, int n) {
    // 512 threads: coalesced partial loads, 64-lane shfl reduce + LDS tree.
    unsigned long long s = 0;
    for (int i = threadIdx.x; i < nblocks; i += 512)
        s += partials[i];
    #pragma unroll
    for (int off = 32; off >= 1; off >>= 1)
        s += __shfl_down(s, off);

    __shared__ unsigned long long s_f[8];
    int wid  = threadIdx.x >> 6;
    int lane = threadIdx.x & 63;
    if (lane == 0) s_f[wid] = s;
    __syncthreads();
    if (threadIdx.x == 0) {
        unsigned long long tot = 0;
        #pragma unroll
        for (int w = 0; w < 8; ++w) tot += s_f[w];
        out[0] = (float)((double)tot / (double)n);
    }
}

extern "C" void kernel_launch(void* const* d_in, const int* in_sizes, int n_in,
                              void* d_out, int out_size, void* d_ws, size_t ws_size,
                              hipStream_t stream) {
    const int*   out_idx = (const int*)d_in[0];
    const int*   tgt_idx = (const int*)d_in[1];
    const float* table   = (const float*)d_in[2];
    float*       out     = (float*)d_out;

    int n = in_sizes[0];

    unsigned long long* codes    = (unsigned long long*)d_ws;
    unsigned long long* partials = (unsigned long long*)((char*)d_ws + 8192);

    // 1) pack table -> u64 codes
    {
        int threads = 256;                               // 4 waves/block
        int blocks = (N_CLASSES * 64 + threads - 1) / threads;  // 250
        pack_init_kernel<<<blocks, threads, 0, stream>>>(table, codes);
    }

    // 2) main reduce -> per-block partials (plain stores, no sync)
    int nblocks;
    {
        int nvec = n / 4;
        int threads = 256;
        nblocks = MAIN_BLOCKS;                           // 1 int4-pair/thread at B=2M
        int max_blocks = (nvec + threads - 1) / threads;
        if (nblocks > max_blocks) nblocks = max_blocks;
        if (nblocks < 1) nblocks = 1;
        hamming_kernel<<<nblocks, threads, 0, stream>>>(
            out_idx, tgt_idx, codes, partials, nvec, n);
    }

    // 3) finalize: sum partials, divide
    finalize_kernel<<<1, 512, 0, stream>>>(partials, out, nblocks, n);
}

// Round 9
// 15.226 us; speedup vs baseline: 1.7513x; 1.0407x over previous
//
#include <hip/hip_runtime.h>

// HammingLoss: loss = mean_i popcount(code[output[i]] ^ code[target[i]])
// code[c] = 64-bit packing of coding_table[c, :] (values are exactly 0.0/1.0).
//
// ZERO-SYNC design — the kernel boundary is the ONLY cross-block release.
// Measured-lever ledger (complete; do not revisit):
//   R4->R5: ~1K device-scope RMW atomics at one address = ~10 us (serialized
//           at the cross-XCD coherence point). No counters, no fetch-add.
//   R6->R7: device-scope release/acquire sentinel polling = +11 us (AGENT-
//           scope stores/loads hammer the same coherence point). In-kernel
//           node fusion is never worth the ~1.1 us a dispatch node costs.
//   Block scan: {512: 16.0, 1024: 15.3, 2048: 15.85} us -> 1024 optimal.
//   KBATCH up-front load batching: null (R3->R4). Finalize widening: -0.7 us.
//
// 3 dispatches (measured best = 15.31 us, R6 config):
//   1) pack_init: table -> packed u64 codes (one 64-lane wave per class,
//      __ballot). Nothing to zero: partials/out are fully rewritten each call.
//   2) hamming: 1024 blocks x KBATCH=2 int4-pairs per thread; loads issued
//      before LDS staging (latency hides under staging + barrier), LDS code
//      table, popcount-XOR, wave+block reduce, plain store of block partial.
//   3) finalize: 512 threads, coalesced partial loads, wave shfl + LDS tree,
//      out = sum / n.
//
// Working set (16.8 MB indices + table) is L2/L3-resident; do NOT use
// nontemporal loads.
//
// ws layout:
//   [0,    8000)   : unsigned long long codes[1000]
//   [8192, 16384)  : unsigned long long partials[MAIN_BLOCKS]

#define N_CLASSES 1000
#define CODE_LEN  64
#define MAIN_BLOCKS 1024
#define KBATCH 2

__global__ void pack_init_kernel(const float* __restrict__ table,
                                 unsigned long long* __restrict__ codes) {
    int gtid = blockIdx.x * blockDim.x + threadIdx.x;
    int wave = gtid >> 6;          // one 64-lane wave per class
    int lane = threadIdx.x & 63;
    if (wave < N_CLASSES) {
        float v = table[wave * CODE_LEN + lane];          // coalesced 256B/wave
        unsigned long long mask = __ballot(v > 0.5f);     // 64-bit ballot
        if (lane == 0) codes[wave] = mask;
    }
}

__global__ void __launch_bounds__(256)
hamming_kernel(const int* __restrict__ out_idx,
               const int* __restrict__ tgt_idx,
               const unsigned long long* __restrict__ codes,
               unsigned long long* __restrict__ partials,
               int nvec, int n) {
    __shared__ unsigned long long s_codes[N_CLASSES];

    const int4* o4 = (const int4*)out_idx;
    const int4* t4 = (const int4*)tgt_idx;

    int tid0   = blockIdx.x * blockDim.x + threadIdx.x;
    int stride = gridDim.x * blockDim.x;

    // Issue all KBATCH iterations' global loads up-front: one latency
    // exposure, hidden under LDS staging + barrier. Static indexing only.
    int4 ob[KBATCH], tb[KBATCH];
    bool vb[KBATCH];
    #pragma unroll
    for (int k = 0; k < KBATCH; ++k) {
        int i = tid0 + k * stride;
        vb[k] = (i < nvec);
        if (vb[k]) { ob[k] = o4[i]; tb[k] = t4[i]; }
    }

    // stage packed table (8 KB) as 16B vectors
    {
        const ulonglong2* src = (const ulonglong2*)codes;
        ulonglong2*       dst = (ulonglong2*)s_codes;
        for (int i = threadIdx.x; i < N_CLASSES / 2; i += blockDim.x)
            dst[i] = src[i];
    }
    __syncthreads();

    int sum = 0;
    #pragma unroll
    for (int k = 0; k < KBATCH; ++k) {
        if (vb[k]) {
            sum += __popcll(s_codes[ob[k].x] ^ s_codes[tb[k].x]);
            sum += __popcll(s_codes[ob[k].y] ^ s_codes[tb[k].y]);
            sum += __popcll(s_codes[ob[k].z] ^ s_codes[tb[k].z]);
            sum += __popcll(s_codes[ob[k].w] ^ s_codes[tb[k].w]);
        }
    }
    // iterations beyond KBATCH (not taken at B=2M with 1024 blocks)
    for (int i = tid0 + KBATCH * stride; i < nvec; i += stride) {
        int4 o = o4[i];
        int4 t = t4[i];
        sum += __popcll(s_codes[o.x] ^ s_codes[t.x]);
        sum += __popcll(s_codes[o.y] ^ s_codes[t.y]);
        sum += __popcll(s_codes[o.z] ^ s_codes[t.z]);
        sum += __popcll(s_codes[o.w] ^ s_codes[t.w]);
    }
    // scalar tail (n % 4)
    for (int i = nvec * 4 + tid0; i < n; i += stride) {
        sum += __popcll(s_codes[out_idx[i]] ^ s_codes[tgt_idx[i]]);
    }

    // 64-lane wave reduce
    #pragma unroll
    for (int off = 32; off >= 1; off >>= 1)
        sum += __shfl_down(sum, off);

    __shared__ int s_part[4];      // 256 threads = 4 waves
    int wid  = threadIdx.x >> 6;
    int lane = threadIdx.x & 63;
    if (lane == 0) s_part[wid] = sum;
    __syncthreads();

    if (threadIdx.x == 0) {
        partials[blockIdx.x] =
            (unsigned long long)(s_part[0] + s_part[1] + s_part[2] + s_part[3]);
    }
}

__global__ void __launch_bounds__(512)
finalize_kernel(const unsigned long long* __restrict__ partials,
                float* __restrict__ out, int nblocks, int n) {
    // 512 threads: one coalesced partial load each, 64-lane shfl reduce +
    // 8-wave LDS tree.
    unsigned long long s = 0;
    for (int i = threadIdx.x; i < nblocks; i += 512)
        s += partials[i];
    #pragma unroll
    for (int off = 32; off >= 1; off >>= 1)
        s += __shfl_down(s, off);

    __shared__ unsigned long long s_f[8];
    int wid  = threadIdx.x >> 6;
    int lane = threadIdx.x & 63;
    if (lane == 0) s_f[wid] = s;
    __syncthreads();
    if (threadIdx.x == 0) {
        unsigned long long tot = 0;
        #pragma unroll
        for (int w = 0; w < 8; ++w) tot += s_f[w];
        out[0] = (float)((double)tot / (double)n);
    }
}

extern "C" void kernel_launch(void* const* d_in, const int* in_sizes, int n_in,
                              void* d_out, int out_size, void* d_ws, size_t ws_size,
                              hipStream_t stream) {
    const int*   out_idx = (const int*)d_in[0];
    const int*   tgt_idx = (const int*)d_in[1];
    const float* table   = (const float*)d_in[2];
    float*       out     = (float*)d_out;

    int n = in_sizes[0];

    unsigned long long* codes    = (unsigned long long*)d_ws;
    unsigned long long* partials = (unsigned long long*)((char*)d_ws + 8192);

    // 1) pack table -> u64 codes
    {
        int threads = 256;                               // 4 waves/block
        int blocks = (N_CLASSES * 64 + threads - 1) / threads;  // 250
        pack_init_kernel<<<blocks, threads, 0, stream>>>(table, codes);
    }

    // 2) main reduce -> per-block partials (plain stores, no sync)
    int nblocks;
    {
        int nvec = n / 4;
        int threads = 256;
        nblocks = MAIN_BLOCKS;                           // 2 int4 iters/thread at B=2M
        int max_blocks = (nvec + threads - 1) / threads;
        if (nblocks > max_blocks) nblocks = max_blocks;
        if (nblocks < 1) nblocks = 1;
        hamming_kernel<<<nblocks, threads, 0, stream>>>(
            out_idx, tgt_idx, codes, partials, nvec, n);
    }

    // 3) finalize: sum partials, divide
    finalize_kernel<<<1, 512, 0, stream>>>(partials, out, nblocks, n);
}